// Round 7
// baseline (257.127 us; speedup 1.0000x reference)
//
#include <hip/hip_runtime.h>
#include <hip/hip_bf16.h>
#include <math.h>

#define N_CELL 76
#define N_DRUG 764
#define N_ITEM 840
#define BATCH  4096

// ws layout (byte offsets)
// Phase A (convs): pool1 f32 [840][64][64][4] : 0 .. 55,050,240
//                  pool2h bf16 [840][8192]    : 55,050,240 .. 68,812,800
//                  pool2l bf16 [840][8192]    : 68,812,800 .. 82,575,360
// Phase B (after conv2, aliases dead pool1):
//                  whi bf16 [64][8192], wlo, xfc, item, emb, V, loss
#define POOL2H_B 55050240u
#define POOL2L_B 68812800u
#define WHI_B    0u
#define WLO_B    1048576u
#define XFC_B    2097152u
#define ITEM_B   2312192u
#define EMB_B    2527232u
#define V_B      2742272u
#define LOSS_B   2781184u

typedef short bh8 __attribute__((ext_vector_type(8)));
typedef short bh4 __attribute__((ext_vector_type(4)));
typedef float f32x4 __attribute__((ext_vector_type(4)));

static __device__ inline unsigned short f2bf(float f) {
  union { float f; unsigned u; } v; v.f = f;
  unsigned r = v.u + 0x7FFFu + ((v.u >> 16) & 1u);  // RNE (no NaN inputs here)
  return (unsigned short)(r >> 16);
}
static __device__ inline float bf2f(unsigned short h) {
  union { unsigned u; float f; } v; v.u = ((unsigned)h) << 16;
  return v.f;
}
// lo residual via truncation (residual <= 2^-9|a|, trunc err <= 2^-17|a|)
static __device__ inline unsigned short f2bf_lo(float f, unsigned short h) {
  union { float f; unsigned u; } a; a.f = f - bf2f(h);
  return (unsigned short)(a.u >> 16);
}

union BH8U { bh8 v; struct { bh4 lo, hi; } s; };

// ---------------- conv1 via MFMA (split bf16, 4-phase reshape) ----------------
// 128 px = 32 groups x 4 phases; LDS [row][group 0..33][4px] h/l planes
// (borders zero). Even set: A[m][k=(r,w)] = in[row][4(x0+m)-4+w], outputs
// px 4(x0+m)+{0,2}; odd set: base 4(x0+m)+w, outputs +{1,3}.
// N=16 = 4oc x 2hi(phase) x 2yv. K=32 = 4 rows x 8 w. Bias in epilogue
// (max(x_i)+b == max(x_i+b), monotone). x-pool = even/odd accs in-lane,
// y-pool via shfl_xor(4). Writes pool1 f32 [py][px][4oc] (conv2's format).
__global__ __launch_bounds__(256) void k_conv1(
    const float* __restrict__ cell_pre, const float* __restrict__ drug_pre,
    const float* __restrict__ w1, const float* __restrict__ b1,
    float* __restrict__ pool1) {
  __shared__ unsigned short lh[66 * 34 * 4];
  __shared__ unsigned short ll[66 * 34 * 4];
  int half = blockIdx.x, n = blockIdx.y;
  int tid = threadIdx.x;
  int cy0 = half * 64;
  const float4* src = (const float4*)((n < N_CELL) ? (cell_pre + (size_t)n * 16384)
                                                   : (drug_pre + (size_t)(n - N_CELL) * 16384));
  for (int i = tid; i < 66 * 32; i += 256) {
    int lr = i >> 5, g = i & 31;
    int iy = cy0 - 1 + lr;
    float4 v = make_float4(0.f, 0.f, 0.f, 0.f);
    if (iy >= 0 && iy < 128) v = src[iy * 32 + g];
    ushort4 h, l;
    h.x = f2bf(v.x); l.x = f2bf_lo(v.x, h.x);
    h.y = f2bf(v.y); l.y = f2bf_lo(v.y, h.y);
    h.z = f2bf(v.z); l.z = f2bf_lo(v.z, h.z);
    h.w = f2bf(v.w); l.w = f2bf_lo(v.w, h.w);
    ((ushort4*)lh)[lr * 34 + g + 1] = h;
    ((ushort4*)ll)[lr * 34 + g + 1] = l;
  }
  if (tid < 132) {
    int lr = tid >> 1, g = (tid & 1) ? 33 : 0;
    ushort4 z = make_ushort4(0, 0, 0, 0);
    ((ushort4*)lh)[lr * 34 + g] = z;
    ((ushort4*)ll)[lr * 34 + g] = z;
  }
  int wv_ = tid >> 6;
  int lane = tid & 63;
  int ml = lane & 15, q = lane >> 4;
  int oc = ml & 3, yv = (ml >> 2) & 1, hi = ml >> 3;
  float bb = b1[oc];
  // ---- B fragments (once; lane = col ml, k = q*8+j; r=q, w=j) ----
  bh8 BhE, BlE, BhO, BlO;
  {
    int kr = q - yv;
    bool krok = (kr >= 0 && kr <= 2);
#pragma unroll
    for (int j = 0; j < 8; ++j) {
      float ve = 0.f, vo = 0.f;
      if (krok) {
        int kse = j - 3 - 2 * hi;   // even phases 0/2: w = pe+ks+3
        int kso = j - 2 * hi;       // odd  phases 1/3: w = po+ks-1
        if (kse >= 0 && kse <= 2) ve = w1[oc * 9 + kr * 3 + kse];
        if (kso >= 0 && kso <= 2) vo = w1[oc * 9 + kr * 3 + kso];
      }
      unsigned short he = f2bf(ve), ho = f2bf(vo);
      BhE[j] = (short)he; BlE[j] = (short)f2bf_lo(ve, he);
      BhO[j] = (short)ho; BlO[j] = (short)f2bf_lo(vo, ho);
    }
  }
  __syncthreads();
  int x0 = (wv_ & 1) * 16;      // group strip
  int rp0 = (wv_ >> 1) * 16;    // pool-row range
  int Lb = x0 + ml;             // LDS group index of first needed group (real g-1 -> +1 shift)
  const bh4* lh4 = (const bh4*)lh;
  const bh4* ll4 = (const bh4*)ll;
#pragma unroll 1
  for (int i = 0; i < 16; ++i) {
    int rp = rp0 + i;
    int lr = 2 * rp + q;        // window row r=q at image row 2rp-1+q -> LDS row 2rp+q
    int base = lr * 34 + Lb;
    bh4 g0h = lh4[base], g1h = lh4[base + 1], g2h = lh4[base + 2];
    bh4 g0l = ll4[base], g1l = ll4[base + 1], g2l = ll4[base + 2];
    BH8U aeh, ael, aoh, aol;
    aeh.s.lo = g0h; aeh.s.hi = g1h;
    ael.s.lo = g0l; ael.s.hi = g1l;
    aoh.s.lo = g1h; aoh.s.hi = g2h;
    aol.s.lo = g1l; aol.s.hi = g2l;
    f32x4 de = {0.f, 0.f, 0.f, 0.f}, dd = de;
    de = __builtin_amdgcn_mfma_f32_16x16x32_bf16(aeh.v, BhE, de, 0, 0, 0);
    de = __builtin_amdgcn_mfma_f32_16x16x32_bf16(aeh.v, BlE, de, 0, 0, 0);
    de = __builtin_amdgcn_mfma_f32_16x16x32_bf16(ael.v, BhE, de, 0, 0, 0);
    dd = __builtin_amdgcn_mfma_f32_16x16x32_bf16(aoh.v, BhO, dd, 0, 0, 0);
    dd = __builtin_amdgcn_mfma_f32_16x16x32_bf16(aoh.v, BlO, dd, 0, 0, 0);
    dd = __builtin_amdgcn_mfma_f32_16x16x32_bf16(aol.v, BhO, dd, 0, 0, 0);
    int py = half * 32 + rp;
#pragma unroll
    for (int r = 0; r < 4; ++r) {
      float t = fmaxf(de[r], dd[r]);        // x-pool (phases pair in-lane)
      float t2 = __shfl_xor(t, 4);          // y-pool partner (yv bit)
      if (yv == 0) {
        float val = fmaxf(fmaxf(t, t2) + bb, 0.f);
        int px = 2 * (x0 + q * 4 + r) + hi; // D row m = q*4+r
        pool1[(((size_t)n * 64 + py) * 64 + px) * 4 + oc] = val;
      }
    }
  }
}

// ---------------- conv2 via MFMA (split bf16) — unchanged, proven R6 ----------------
__global__ __launch_bounds__(256) void k_conv2(
    const float* __restrict__ pool1, const float* __restrict__ w2,
    const float* __restrict__ b2, unsigned short* __restrict__ pool2h,
    unsigned short* __restrict__ pool2l) {
  __shared__ unsigned short lh[34 * 66 * 4];
  __shared__ unsigned short ll[34 * 66 * 4];
  int half = blockIdx.x, n = blockIdx.y;
  int tid = threadIdx.x;
  int cy0 = half * 32;
  const float4* src = (const float4*)(pool1 + (size_t)n * 16384);
  for (int i = tid; i < 34 * 64; i += 256) {
    int r = i >> 6, c = i & 63;
    int iy = cy0 - 1 + r;
    float4 v = make_float4(0.f, 0.f, 0.f, 0.f);
    if (iy >= 0 && iy < 64) v = src[iy * 64 + c];
    ushort4 h, l;
    h.x = f2bf(v.x); l.x = f2bf_lo(v.x, h.x);
    h.y = f2bf(v.y); l.y = f2bf_lo(v.y, h.y);
    h.z = f2bf(v.z); l.z = f2bf_lo(v.z, h.z);
    h.w = f2bf(v.w); l.w = f2bf_lo(v.w, h.w);
    ((ushort4*)lh)[r * 66 + c + 1] = h;
    ((ushort4*)ll)[r * 66 + c + 1] = l;
  }
  if (tid < 68) {
    int r = tid >> 1, c = (tid & 1) ? 65 : 0;
    ushort4 z = make_ushort4(0, 0, 0, 0);
    ((ushort4*)lh)[r * 66 + c] = z;
    ((ushort4*)ll)[r * 66 + c] = z;
  }
  int wv_ = tid >> 6;
  int lane = tid & 63;
  int ml = lane & 15, q = lane >> 4;
  int oc_b = ml & 7, yv = ml >> 3;
  bh8 Bh[2], Bl[2];
#pragma unroll
  for (int ch = 0; ch < 2; ++ch) {
#pragma unroll
    for (int j = 0; j < 8; ++j) {
      int kg = ch * 32 + q * 8 + j;
      float v = 0.f;
      if (kg < 48) {
        int r = kg / 12, rem = kg - r * 12;
        int ks = rem >> 2, ic = rem & 3;
        int kr = r - yv;
        if (kr >= 0 && kr <= 2) v = w2[(oc_b * 4 + ic) * 9 + kr * 3 + ks];
      } else if (kg == 48) {
        v = b2[oc_b];
      }
      unsigned short h = f2bf(v);
      Bh[ch][j] = (short)h;
      Bl[ch][j] = (short)f2bf_lo(v, h);
    }
  }
  int c0 = 2 * q, c1 = 2 * q + 1;
  int c2 = 8 + 2 * q, c3 = 9 + 2 * q;
  if (c2 > 11) { c2 = 8; c3 = 9; }
  int r0 = (c0 * 86) >> 8, s0 = c0 - 3 * r0;
  int r1 = (c1 * 86) >> 8, s1 = c1 - 3 * r1;
  int r2 = (c2 * 86) >> 8, s2 = c2 - 3 * r2;
  int r3 = (c3 * 86) >> 8, s3 = c3 - 3 * r3;
  int x0 = (wv_ & 3) << 4;
  int off0 = r0 * 66 + x0 + ml + s0;
  int off1 = r1 * 66 + x0 + ml + s1;
  int off2 = r2 * 66 + x0 + ml + s2;
  int off3 = r3 * 66 + x0 + ml + s3;
  __syncthreads();
  const bh4* lh4 = (const bh4*)lh;
  const bh4* ll4 = (const bh4*)ll;
#pragma unroll 1
  for (int rp = 0; rp < 16; ++rp) {
    int base = 2 * rp * 66;
    BH8U ah0, al0, ah1, al1;
    ah0.s.lo = lh4[base + off0]; ah0.s.hi = lh4[base + off1];
    al0.s.lo = ll4[base + off0]; al0.s.hi = ll4[base + off1];
    if (q < 2) {
      ah1.s.lo = lh4[base + off2]; ah1.s.hi = lh4[base + off3];
      al1.s.lo = ll4[base + off2]; al1.s.hi = ll4[base + off3];
    } else {
#pragma unroll
      for (int j = 0; j < 8; ++j) { ah1.v[j] = 0; al1.v[j] = 0; }
      if (q == 2) ah1.v[0] = (short)0x3F80;  // bf16 1.0 -> bias row k=48
    }
    f32x4 accA = {0.f, 0.f, 0.f, 0.f}, accB = accA;
    accA = __builtin_amdgcn_mfma_f32_16x16x32_bf16(ah0.v, Bh[0], accA, 0, 0, 0);
    accA = __builtin_amdgcn_mfma_f32_16x16x32_bf16(ah0.v, Bl[0], accA, 0, 0, 0);
    accA = __builtin_amdgcn_mfma_f32_16x16x32_bf16(al0.v, Bh[0], accA, 0, 0, 0);
    accB = __builtin_amdgcn_mfma_f32_16x16x32_bf16(ah1.v, Bh[1], accB, 0, 0, 0);
    accB = __builtin_amdgcn_mfma_f32_16x16x32_bf16(ah1.v, Bl[1], accB, 0, 0, 0);
    accB = __builtin_amdgcn_mfma_f32_16x16x32_bf16(al1.v, Bh[1], accB, 0, 0, 0);
    float d0 = accA[0] + accB[0], d1 = accA[1] + accB[1];
    float d2 = accA[2] + accB[2], d3 = accA[3] + accB[3];
    float m0 = fmaxf(d0, d1), m1 = fmaxf(d2, d3);
    float o0 = __shfl_xor(m0, 8), o1 = __shfl_xor(m1, 8);
    m0 = fmaxf(fmaxf(m0, o0), 0.f);
    m1 = fmaxf(fmaxf(m1, o1), 0.f);
    if (yv == 0) {
      unsigned short h0 = f2bf(m0), h1 = f2bf(m1);
      unsigned short l0 = f2bf(m0 - bf2f(h0)), l1 = f2bf(m1 - bf2f(h1));
      int PR = half * 16 + rp;
      unsigned ui = (unsigned)n * 4096u + (unsigned)oc_b * 512u +
                    (unsigned)PR * 16u + (unsigned)(x0 >> 2) + (unsigned)q;
      ((unsigned*)pool2h)[ui] = (unsigned)h0 | ((unsigned)h1 << 16);
      ((unsigned*)pool2l)[ui] = (unsigned)l0 | ((unsigned)l1 << 16);
    }
  }
}

// ---------------- cast out_w -> split bf16; zero xfc & loss ----------------
__global__ __launch_bounds__(256) void k_cast(
    const float* __restrict__ out_w, unsigned short* __restrict__ whi,
    unsigned short* __restrict__ wlo, float* __restrict__ xfc,
    float* __restrict__ loss) {
  int gid = blockIdx.x * 256 + threadIdx.x;  // 131072 = 524288/4
  if (gid == 0) *loss = 0.f;
  float4 v = ((const float4*)out_w)[gid];
  ushort4 h, l;
  h.x = f2bf(v.x); l.x = f2bf(v.x - bf2f(h.x));
  h.y = f2bf(v.y); l.y = f2bf(v.y - bf2f(h.y));
  h.z = f2bf(v.z); l.z = f2bf(v.z - bf2f(h.z));
  h.w = f2bf(v.w); l.w = f2bf(v.w - bf2f(h.w));
  ((ushort4*)whi)[gid] = h;
  ((ushort4*)wlo)[gid] = l;
  if (gid < N_ITEM * 64) xfc[gid] = 0.f;
}

// ---------------- FC: split-bf16 MFMA GEMM, M=840 N=64, K chunks of 256 ----------------
__global__ __launch_bounds__(64) void k_fc(
    const unsigned short* __restrict__ pool2h, const unsigned short* __restrict__ pool2l,
    const unsigned short* __restrict__ whi, const unsigned short* __restrict__ wlo,
    float* __restrict__ xfc) {
  int mt = blockIdx.x, kc = blockIdx.y;
  int lane = threadIdx.x;
  int ml = lane & 15, q = lane >> 4;
  int row = mt * 16 + ml; if (row > N_ITEM - 1) row = N_ITEM - 1;
  size_t k0 = (size_t)kc * 256 + q * 8;
  const bh8* Ah = (const bh8*)(pool2h + (size_t)row * 8192 + k0);
  const bh8* Al = (const bh8*)(pool2l + (size_t)row * 8192 + k0);
  const bh8* Bh[4], * Bl[4];
#pragma unroll
  for (int nb = 0; nb < 4; ++nb) {
    Bh[nb] = (const bh8*)(whi + (size_t)(nb * 16 + ml) * 8192 + k0);
    Bl[nb] = (const bh8*)(wlo + (size_t)(nb * 16 + ml) * 8192 + k0);
  }
  f32x4 acc[4];
#pragma unroll
  for (int nb = 0; nb < 4; ++nb) acc[nb] = (f32x4){0.f, 0.f, 0.f, 0.f};
#pragma unroll
  for (int st = 0; st < 8; ++st) {
    bh8 ah = Ah[st * 4], al = Al[st * 4];
#pragma unroll
    for (int nb = 0; nb < 4; ++nb) {
      bh8 bhv = Bh[nb][st * 4], blv = Bl[nb][st * 4];
      acc[nb] = __builtin_amdgcn_mfma_f32_16x16x32_bf16(ah, bhv, acc[nb], 0, 0, 0);
      acc[nb] = __builtin_amdgcn_mfma_f32_16x16x32_bf16(ah, blv, acc[nb], 0, 0, 0);
      acc[nb] = __builtin_amdgcn_mfma_f32_16x16x32_bf16(al, bhv, acc[nb], 0, 0, 0);
    }
  }
#pragma unroll
  for (int r = 0; r < 4; ++r) {
    int mr = mt * 16 + q * 4 + r;
    if (mr < N_ITEM) {
      float* dst = xfc + (size_t)mr * 64 + ml;
#pragma unroll
      for (int nb = 0; nb < 4; ++nb) atomicAdd(dst + nb * 16, acc[nb][r]);
    }
  }
}

// ---------------- per-group, per-column batch norm (ddof=1) ----------------
__global__ __launch_bounds__(256) void k_norm(
    const float* __restrict__ xfc, float* __restrict__ item) {
  __shared__ float red[256];
  int grp = blockIdx.x >> 6;
  int o = blockIdx.x & 63;
  int base = grp ? N_CELL : 0;
  int N = grp ? N_DRUG : N_CELL;
  int tid = threadIdx.x;
  float s = 0.f;
  for (int i = tid; i < N; i += 256) s += xfc[(size_t)(base + i) * 64 + o];
  red[tid] = s; __syncthreads();
  for (int w = 128; w > 0; w >>= 1) { if (tid < w) red[tid] += red[tid + w]; __syncthreads(); }
  float mean = red[0] / (float)N;
  __syncthreads();
  float sq = 0.f;
  for (int i = tid; i < N; i += 256) {
    float d = xfc[(size_t)(base + i) * 64 + o] - mean;
    sq += d * d;
  }
  red[tid] = sq; __syncthreads();
  for (int w = 128; w > 0; w >>= 1) { if (tid < w) red[tid] += red[tid + w]; __syncthreads(); }
  float inv_std = 1.f / sqrtf(red[0] / (float)(N - 1));
  for (int i = tid; i < N; i += 256)
    item[(size_t)(base + i) * 64 + o] = (xfc[(size_t)(base + i) * 64 + o] - mean) * inv_std;
}

// ---------------- interact (2-hop attention) + agg GEMV ----------------
__global__ __launch_bounds__(256) void k_interact(
    const int* __restrict__ cell_nbr, const int* __restrict__ drug_nbr,
    const float* __restrict__ protein, const float* __restrict__ item,
    const float* __restrict__ agg_w, const float* __restrict__ agg_b,
    float* __restrict__ emb) {
  __shared__ float pb[128 * 65];
  __shared__ float item_s[64];
  __shared__ float sc[128];
  __shared__ float hop_out[128];
  __shared__ float red[256];
  int n = blockIdx.x;
  int tid = threadIdx.x;
  const int* nbr = (n < N_CELL) ? (cell_nbr + (size_t)n * 256)
                                : (drug_nbr + (size_t)(n - N_CELL) * 256);
  if (tid < 64) item_s[tid] = item[(size_t)n * 64 + tid];
  __syncthreads();
  for (int h = 0; h < 2; ++h) {
    for (int e = tid; e < 8192; e += 256) {
      int k = e >> 6, d = e & 63;
      int idx = nbr[h * 128 + k];
      pb[k * 65 + d] = protein[(size_t)idx * 64 + d];
    }
    __syncthreads();
    {
      int k = tid >> 1, halfd = tid & 1;
      int d0 = halfd * 32;
      float p = 0.f;
#pragma unroll
      for (int d = 0; d < 32; ++d) p += item_s[d0 + d] * pb[k * 65 + d0 + d];
      p += __shfl_xor(p, 1);
      if (halfd == 0) sc[k] = p;
    }
    __syncthreads();
    if (tid < 64) {
      float a = sc[tid], b = sc[tid + 64];
      float m = fmaxf(a, b);
#pragma unroll
      for (int off = 32; off > 0; off >>= 1) m = fmaxf(m, __shfl_xor(m, off));
      float e0 = __expf(a - m), e1 = __expf(b - m);
      float s = e0 + e1;
#pragma unroll
      for (int off = 32; off > 0; off >>= 1) s += __shfl_xor(s, off);
      float inv = 1.f / s;
      sc[tid] = e0 * inv; sc[tid + 64] = e1 * inv;
    }
    __syncthreads();
    {
      int d = tid & 63, kq = tid >> 6;
      float p = 0.f;
#pragma unroll
      for (int k = 0; k < 32; ++k) {
        int kk = kq * 32 + k;
        p += sc[kk] * pb[kk * 65 + d];
      }
      red[tid] = p;
    }
    __syncthreads();
    if (tid < 64)
      hop_out[h * 64 + tid] = red[tid] + red[tid + 64] + red[tid + 128] + red[tid + 192];
    __syncthreads();
  }
  {
    int o = tid & 63, jq = tid >> 6;
    float p = 0.f;
#pragma unroll
    for (int j = 0; j < 32; ++j) {
      int jj = jq * 32 + j;
      p += hop_out[jj] * agg_w[(size_t)o * 128 + jj];
    }
    red[tid] = p;
  }
  __syncthreads();
  if (tid < 64)
    emb[(size_t)n * 64 + tid] =
        red[tid] + red[tid + 64] + red[tid + 128] + red[tid + 192] + agg_b[tid];
}

// ---------------- precompute V[c] = comb_w^T @ cell_emb[c]  (76 x 128) ----------------
__global__ __launch_bounds__(128) void k_cellv(
    const float* __restrict__ emb, const float* __restrict__ comb_w,
    float* __restrict__ V) {
  __shared__ float ce[64];
  int c = blockIdx.x;
  int j = threadIdx.x;
  if (j < 64) ce[j] = emb[(size_t)c * 64 + j];
  __syncthreads();
  float s = 0.f;
#pragma unroll
  for (int o = 0; o < 64; ++o) s += comb_w[(size_t)o * 128 + j] * ce[o];
  V[(size_t)c * 128 + j] = s;
}

// ---------------- final scoring: therapy = cat(e1,e2) . V[c], toxic = e1.e2 ----------------
__global__ __launch_bounds__(256) void k_score(
    const int* __restrict__ data, const float* __restrict__ emb,
    const float* __restrict__ V, float* __restrict__ out,
    float* __restrict__ loss) {
  __shared__ float racc[4];
  int tid = threadIdx.x;
  int lane = tid & 63;
  int w = tid >> 6;
  int b = blockIdx.x * 4 + w;
  int c = data[b * 3 + 0], d1 = data[b * 3 + 1], d2 = data[b * 3 + 2];
  float ce = emb[(size_t)c * 64 + lane];
  float e1 = emb[(size_t)(N_CELL + d1) * 64 + lane];
  float e2 = emb[(size_t)(N_CELL + d2) * 64 + lane];
  float v1 = V[(size_t)c * 128 + lane];
  float v2 = V[(size_t)c * 128 + 64 + lane];
  float th = e1 * v1 + e2 * v2;
  float tx = e1 * e2;
  float rg = ce * ce + e1 * e1 + e2 * e2;
#pragma unroll
  for (int off = 32; off > 0; off >>= 1) {
    th += __shfl_xor(th, off);
    tx += __shfl_xor(tx, off);
    rg += __shfl_xor(rg, off);
  }
  if (lane == 0) { out[b] = th - tx; racc[w] = rg; }
  __syncthreads();
  if (tid == 0) atomicAdd(loss, 0.5f * (racc[0] + racc[1] + racc[2] + racc[3]));
}

// ---------------- node regularization (6 gathered rows) ----------------
__global__ __launch_bounds__(256) void k_nodereg(
    const int* __restrict__ data, const int* __restrict__ cell_nbr,
    const int* __restrict__ drug_nbr, const float* __restrict__ protein,
    float* __restrict__ loss) {
  __shared__ float red[256];
  int j = blockIdx.x;  // 0..5
  int hop = j / 3, which = j % 3;
  int row = data[hop * 3 + which];
  const int* nbr = (which == 0) ? (cell_nbr + (size_t)row * 256)
                                : (drug_nbr + (size_t)row * 256);
  int tid = threadIdx.x;
  float acc = 0.f;
  for (int e = tid; e < 16384; e += 256) {
    int k = e >> 6, d = e & 63;
    float v = protein[(size_t)nbr[k] * 64 + d];
    acc += v * v;
  }
  red[tid] = acc; __syncthreads();
  for (int w = 128; w > 0; w >>= 1) { if (tid < w) red[tid] += red[tid + w]; __syncthreads(); }
  if (tid == 0) atomicAdd(loss, 0.5f * red[0]);
}

__global__ void k_finalize(const float* __restrict__ loss, float* __restrict__ out) {
  if (threadIdx.x == 0) out[BATCH] = loss[0] * (1e-6f / 4096.f);
}

extern "C" void kernel_launch(void* const* d_in, const int* in_sizes, int n_in,
                              void* d_out, int out_size, void* d_ws, size_t ws_size,
                              hipStream_t stream) {
  const int*   data      = (const int*)d_in[0];
  const int*   cell_nbr  = (const int*)d_in[1];
  const int*   drug_nbr  = (const int*)d_in[2];
  const float* protein   = (const float*)d_in[3];
  const float* cell_pre  = (const float*)d_in[4];
  const float* drug_pre  = (const float*)d_in[5];
  const float* w1        = (const float*)d_in[6];
  const float* b1        = (const float*)d_in[7];
  const float* w2        = (const float*)d_in[8];
  const float* b2        = (const float*)d_in[9];
  const float* out_w     = (const float*)d_in[10];
  const float* agg_w     = (const float*)d_in[12];
  const float* agg_b     = (const float*)d_in[13];
  const float* comb_w    = (const float*)d_in[14];
  float* out = (float*)d_out;
  char* base = (char*)d_ws;
  float* pool1            = (float*)base;
  unsigned short* pool2h  = (unsigned short*)(base + POOL2H_B);
  unsigned short* pool2l  = (unsigned short*)(base + POOL2L_B);
  unsigned short* whi     = (unsigned short*)(base + WHI_B);
  unsigned short* wlo     = (unsigned short*)(base + WLO_B);
  float* xfc              = (float*)(base + XFC_B);
  float* item             = (float*)(base + ITEM_B);
  float* emb              = (float*)(base + EMB_B);
  float* V                = (float*)(base + V_B);
  float* loss             = (float*)(base + LOSS_B);

  k_conv1<<<dim3(2, 840), 256, 0, stream>>>(cell_pre, drug_pre, w1, b1, pool1);
  k_conv2<<<dim3(2, 840), 256, 0, stream>>>(pool1, w2, b2, pool2h, pool2l);
  k_cast<<<512, 256, 0, stream>>>(out_w, whi, wlo, xfc, loss);
  k_fc<<<dim3(53, 32), 64, 0, stream>>>(pool2h, pool2l, whi, wlo, xfc);
  k_norm<<<128, 256, 0, stream>>>(xfc, item);
  k_interact<<<840, 256, 0, stream>>>(cell_nbr, drug_nbr, protein, item, agg_w, agg_b, emb);
  k_cellv<<<N_CELL, 128, 0, stream>>>(emb, comb_w, V);
  k_score<<<1024, 256, 0, stream>>>(data, emb, V, out, loss);
  k_nodereg<<<6, 256, 0, stream>>>(data, cell_nbr, drug_nbr, protein, loss);
  k_finalize<<<1, 64, 0, stream>>>(loss, out);
}

// Round 8
// 254.451 us; speedup vs baseline: 1.0105x; 1.0105x over previous
//
#include <hip/hip_runtime.h>
#include <hip/hip_bf16.h>
#include <math.h>

#define N_CELL 76
#define N_DRUG 764
#define N_ITEM 840
#define BATCH  4096

// ws layout (byte offsets)
// Phase A (convs): pool1 f32 [840][64][64][4] : 0 .. 55,050,240
//                  pool2h bf16 [840][8192]    : 55,050,240 .. 68,812,800
//                  pool2l bf16 [840][8192]    : 68,812,800 .. 82,575,360
// Phase B (after conv2, aliases dead pool1):
//                  whi bf16 [64][8192], wlo, xfc, item, emb, V, loss
#define POOL2H_B 55050240u
#define POOL2L_B 68812800u
#define WHI_B    0u
#define WLO_B    1048576u
#define XFC_B    2097152u
#define ITEM_B   2312192u
#define EMB_B    2527232u
#define V_B      2742272u
#define LOSS_B   2781184u

typedef short bh8 __attribute__((ext_vector_type(8)));
typedef short bh4 __attribute__((ext_vector_type(4)));
typedef float f32x4 __attribute__((ext_vector_type(4)));

static __device__ inline unsigned short f2bf(float f) {
  union { float f; unsigned u; } v; v.f = f;
  unsigned r = v.u + 0x7FFFu + ((v.u >> 16) & 1u);  // RNE (no NaN inputs here)
  return (unsigned short)(r >> 16);
}
static __device__ inline float bf2f(unsigned short h) {
  union { unsigned u; float f; } v; v.u = ((unsigned)h) << 16;
  return v.f;
}
// lo residual via truncation (residual <= 2^-9|a|, trunc err <= 2^-17|a|)
static __device__ inline unsigned short f2bf_lo(float f, unsigned short h) {
  union { float f; unsigned u; } a; a.f = f - bf2f(h);
  return (unsigned short)(a.u >> 16);
}

union BH8U { bh8 v; struct { bh4 lo, hi; } s; };

// ---------------- conv1 via MFMA (split bf16, 4-phase reshape) ----------------
// QUARTER-image blocks (R8): LDS 18.5 KB -> 8 blocks/CU for latency hiding.
// Block = 16 pool rows x 64 pool px. Wave = 8 pool rows x 32 pool px.
__global__ __launch_bounds__(256) void k_conv1(
    const float* __restrict__ cell_pre, const float* __restrict__ drug_pre,
    const float* __restrict__ w1, const float* __restrict__ b1,
    float* __restrict__ pool1) {
  __shared__ unsigned short lh[34 * 34 * 4];
  __shared__ unsigned short ll[34 * 34 * 4];
  int quarter = blockIdx.x, n = blockIdx.y;
  int tid = threadIdx.x;
  int cy0 = quarter * 32;  // base conv row of this quarter
  const float4* src = (const float4*)((n < N_CELL) ? (cell_pre + (size_t)n * 16384)
                                                   : (drug_pre + (size_t)(n - N_CELL) * 16384));
  for (int i = tid; i < 34 * 32; i += 256) {
    int lr = i >> 5, g = i & 31;
    int iy = cy0 - 1 + lr;
    float4 v = make_float4(0.f, 0.f, 0.f, 0.f);
    if (iy >= 0 && iy < 128) v = src[iy * 32 + g];
    ushort4 h, l;
    h.x = f2bf(v.x); l.x = f2bf_lo(v.x, h.x);
    h.y = f2bf(v.y); l.y = f2bf_lo(v.y, h.y);
    h.z = f2bf(v.z); l.z = f2bf_lo(v.z, h.z);
    h.w = f2bf(v.w); l.w = f2bf_lo(v.w, h.w);
    ((ushort4*)lh)[lr * 34 + g + 1] = h;
    ((ushort4*)ll)[lr * 34 + g + 1] = l;
  }
  if (tid < 68) {
    int lr = tid >> 1, g = (tid & 1) ? 33 : 0;
    ushort4 z = make_ushort4(0, 0, 0, 0);
    ((ushort4*)lh)[lr * 34 + g] = z;
    ((ushort4*)ll)[lr * 34 + g] = z;
  }
  int wv_ = tid >> 6;
  int lane = tid & 63;
  int ml = lane & 15, q = lane >> 4;
  int oc = ml & 3, yv = (ml >> 2) & 1, hi = ml >> 3;
  float bb = b1[oc];
  // ---- B fragments (once; lane = col ml, k = q*8+j; r=q, w=j) ----
  bh8 BhE, BlE, BhO, BlO;
  {
    int kr = q - yv;
    bool krok = (kr >= 0 && kr <= 2);
#pragma unroll
    for (int j = 0; j < 8; ++j) {
      float ve = 0.f, vo = 0.f;
      if (krok) {
        int kse = j - 3 - 2 * hi;   // even phases 0/2: w = pe+ks+3
        int kso = j - 2 * hi;       // odd  phases 1/3: w = po+ks-1
        if (kse >= 0 && kse <= 2) ve = w1[oc * 9 + kr * 3 + kse];
        if (kso >= 0 && kso <= 2) vo = w1[oc * 9 + kr * 3 + kso];
      }
      unsigned short he = f2bf(ve), ho = f2bf(vo);
      BhE[j] = (short)he; BlE[j] = (short)f2bf_lo(ve, he);
      BhO[j] = (short)ho; BlO[j] = (short)f2bf_lo(vo, ho);
    }
  }
  __syncthreads();
  int x0 = (wv_ & 1) * 16;     // group strip
  int rp0 = (wv_ >> 1) * 8;    // local pool-row range (8 rows/wave)
  int Lb = x0 + ml;
  const bh4* lh4 = (const bh4*)lh;
  const bh4* ll4 = (const bh4*)ll;
#pragma unroll 1
  for (int i = 0; i < 8; ++i) {
    int rp = rp0 + i;           // local pool row 0..15
    int lr = 2 * rp + q;
    int base = lr * 34 + Lb;
    bh4 g0h = lh4[base], g1h = lh4[base + 1], g2h = lh4[base + 2];
    bh4 g0l = ll4[base], g1l = ll4[base + 1], g2l = ll4[base + 2];
    BH8U aeh, ael, aoh, aol;
    aeh.s.lo = g0h; aeh.s.hi = g1h;
    ael.s.lo = g0l; ael.s.hi = g1l;
    aoh.s.lo = g1h; aoh.s.hi = g2h;
    aol.s.lo = g1l; aol.s.hi = g2l;
    f32x4 de = {0.f, 0.f, 0.f, 0.f}, dd = de;
    de = __builtin_amdgcn_mfma_f32_16x16x32_bf16(aeh.v, BhE, de, 0, 0, 0);
    de = __builtin_amdgcn_mfma_f32_16x16x32_bf16(aeh.v, BlE, de, 0, 0, 0);
    de = __builtin_amdgcn_mfma_f32_16x16x32_bf16(ael.v, BhE, de, 0, 0, 0);
    dd = __builtin_amdgcn_mfma_f32_16x16x32_bf16(aoh.v, BhO, dd, 0, 0, 0);
    dd = __builtin_amdgcn_mfma_f32_16x16x32_bf16(aoh.v, BlO, dd, 0, 0, 0);
    dd = __builtin_amdgcn_mfma_f32_16x16x32_bf16(aol.v, BhO, dd, 0, 0, 0);
    int py = quarter * 16 + rp;
#pragma unroll
    for (int r = 0; r < 4; ++r) {
      float t = fmaxf(de[r], dd[r]);        // x-pool (phases pair in-lane)
      float t2 = __shfl_xor(t, 4);          // y-pool partner (yv bit)
      if (yv == 0) {
        float val = fmaxf(fmaxf(t, t2) + bb, 0.f);
        int px = 2 * (x0 + q * 4 + r) + hi; // D row m = q*4+r
        pool1[(((size_t)n * 64 + py) * 64 + px) * 4 + oc] = val;
      }
    }
  }
}

// ---------------- conv2 via MFMA (split bf16) — quarter blocks (R8) ----------------
__global__ __launch_bounds__(256) void k_conv2(
    const float* __restrict__ pool1, const float* __restrict__ w2,
    const float* __restrict__ b2, unsigned short* __restrict__ pool2h,
    unsigned short* __restrict__ pool2l) {
  __shared__ unsigned short lh[18 * 66 * 4];
  __shared__ unsigned short ll[18 * 66 * 4];
  int quarter = blockIdx.x, n = blockIdx.y;
  int tid = threadIdx.x;
  int cy0 = quarter * 16;  // base pool1 (conv-input) row
  const float4* src = (const float4*)(pool1 + (size_t)n * 16384);
  for (int i = tid; i < 18 * 64; i += 256) {
    int r = i >> 6, c = i & 63;
    int iy = cy0 - 1 + r;
    float4 v = make_float4(0.f, 0.f, 0.f, 0.f);
    if (iy >= 0 && iy < 64) v = src[iy * 64 + c];
    ushort4 h, l;
    h.x = f2bf(v.x); l.x = f2bf_lo(v.x, h.x);
    h.y = f2bf(v.y); l.y = f2bf_lo(v.y, h.y);
    h.z = f2bf(v.z); l.z = f2bf_lo(v.z, h.z);
    h.w = f2bf(v.w); l.w = f2bf_lo(v.w, h.w);
    ((ushort4*)lh)[r * 66 + c + 1] = h;
    ((ushort4*)ll)[r * 66 + c + 1] = l;
  }
  if (tid < 36) {
    int r = tid >> 1, c = (tid & 1) ? 65 : 0;
    ushort4 z = make_ushort4(0, 0, 0, 0);
    ((ushort4*)lh)[r * 66 + c] = z;
    ((ushort4*)ll)[r * 66 + c] = z;
  }
  int wv_ = tid >> 6;
  int lane = tid & 63;
  int ml = lane & 15, q = lane >> 4;
  int oc_b = ml & 7, yv = ml >> 3;
  bh8 Bh[2], Bl[2];
#pragma unroll
  for (int ch = 0; ch < 2; ++ch) {
#pragma unroll
    for (int j = 0; j < 8; ++j) {
      int kg = ch * 32 + q * 8 + j;
      float v = 0.f;
      if (kg < 48) {
        int r = kg / 12, rem = kg - r * 12;
        int ks = rem >> 2, ic = rem & 3;
        int kr = r - yv;
        if (kr >= 0 && kr <= 2) v = w2[(oc_b * 4 + ic) * 9 + kr * 3 + ks];
      } else if (kg == 48) {
        v = b2[oc_b];
      }
      unsigned short h = f2bf(v);
      Bh[ch][j] = (short)h;
      Bl[ch][j] = (short)f2bf_lo(v, h);
    }
  }
  int c0 = 2 * q, c1 = 2 * q + 1;
  int c2 = 8 + 2 * q, c3 = 9 + 2 * q;
  if (c2 > 11) { c2 = 8; c3 = 9; }
  int r0 = (c0 * 86) >> 8, s0 = c0 - 3 * r0;
  int r1 = (c1 * 86) >> 8, s1 = c1 - 3 * r1;
  int r2 = (c2 * 86) >> 8, s2 = c2 - 3 * r2;
  int r3 = (c3 * 86) >> 8, s3 = c3 - 3 * r3;
  int x0 = (wv_ & 3) << 4;
  int off0 = r0 * 66 + x0 + ml + s0;
  int off1 = r1 * 66 + x0 + ml + s1;
  int off2 = r2 * 66 + x0 + ml + s2;
  int off3 = r3 * 66 + x0 + ml + s3;
  __syncthreads();
  const bh4* lh4 = (const bh4*)lh;
  const bh4* ll4 = (const bh4*)ll;
#pragma unroll 1
  for (int rp = 0; rp < 8; ++rp) {
    int base = 2 * rp * 66;
    BH8U ah0, al0, ah1, al1;
    ah0.s.lo = lh4[base + off0]; ah0.s.hi = lh4[base + off1];
    al0.s.lo = ll4[base + off0]; al0.s.hi = ll4[base + off1];
    if (q < 2) {
      ah1.s.lo = lh4[base + off2]; ah1.s.hi = lh4[base + off3];
      al1.s.lo = ll4[base + off2]; al1.s.hi = ll4[base + off3];
    } else {
#pragma unroll
      for (int j = 0; j < 8; ++j) { ah1.v[j] = 0; al1.v[j] = 0; }
      if (q == 2) ah1.v[0] = (short)0x3F80;  // bf16 1.0 -> bias row k=48
    }
    f32x4 accA = {0.f, 0.f, 0.f, 0.f}, accB = accA;
    accA = __builtin_amdgcn_mfma_f32_16x16x32_bf16(ah0.v, Bh[0], accA, 0, 0, 0);
    accA = __builtin_amdgcn_mfma_f32_16x16x32_bf16(ah0.v, Bl[0], accA, 0, 0, 0);
    accA = __builtin_amdgcn_mfma_f32_16x16x32_bf16(al0.v, Bh[0], accA, 0, 0, 0);
    accB = __builtin_amdgcn_mfma_f32_16x16x32_bf16(ah1.v, Bh[1], accB, 0, 0, 0);
    accB = __builtin_amdgcn_mfma_f32_16x16x32_bf16(ah1.v, Bl[1], accB, 0, 0, 0);
    accB = __builtin_amdgcn_mfma_f32_16x16x32_bf16(al1.v, Bh[1], accB, 0, 0, 0);
    float d0 = accA[0] + accB[0], d1 = accA[1] + accB[1];
    float d2 = accA[2] + accB[2], d3 = accA[3] + accB[3];
    float m0 = fmaxf(d0, d1), m1 = fmaxf(d2, d3);
    float o0 = __shfl_xor(m0, 8), o1 = __shfl_xor(m1, 8);
    m0 = fmaxf(fmaxf(m0, o0), 0.f);
    m1 = fmaxf(fmaxf(m1, o1), 0.f);
    if (yv == 0) {
      unsigned short h0 = f2bf(m0), h1 = f2bf(m1);
      unsigned short l0 = f2bf(m0 - bf2f(h0)), l1 = f2bf(m1 - bf2f(h1));
      int PR = quarter * 8 + rp;
      unsigned ui = (unsigned)n * 4096u + (unsigned)oc_b * 512u +
                    (unsigned)PR * 16u + (unsigned)(x0 >> 2) + (unsigned)q;
      ((unsigned*)pool2h)[ui] = (unsigned)h0 | ((unsigned)h1 << 16);
      ((unsigned*)pool2l)[ui] = (unsigned)l0 | ((unsigned)l1 << 16);
    }
  }
}

// ---------------- cast out_w -> split bf16; zero xfc & loss ----------------
__global__ __launch_bounds__(256) void k_cast(
    const float* __restrict__ out_w, unsigned short* __restrict__ whi,
    unsigned short* __restrict__ wlo, float* __restrict__ xfc,
    float* __restrict__ loss) {
  int gid = blockIdx.x * 256 + threadIdx.x;  // 131072 = 524288/4
  if (gid == 0) *loss = 0.f;
  float4 v = ((const float4*)out_w)[gid];
  ushort4 h, l;
  h.x = f2bf(v.x); l.x = f2bf(v.x - bf2f(h.x));
  h.y = f2bf(v.y); l.y = f2bf(v.y - bf2f(h.y));
  h.z = f2bf(v.z); l.z = f2bf(v.z - bf2f(h.z));
  h.w = f2bf(v.w); l.w = f2bf(v.w - bf2f(h.w));
  ((ushort4*)whi)[gid] = h;
  ((ushort4*)wlo)[gid] = l;
  if (gid < N_ITEM * 64) xfc[gid] = 0.f;
}

// ---------------- FC: split-bf16 MFMA GEMM, M=840 N=64, K chunks of 256 ----------------
__global__ __launch_bounds__(64) void k_fc(
    const unsigned short* __restrict__ pool2h, const unsigned short* __restrict__ pool2l,
    const unsigned short* __restrict__ whi, const unsigned short* __restrict__ wlo,
    float* __restrict__ xfc) {
  int mt = blockIdx.x, kc = blockIdx.y;
  int lane = threadIdx.x;
  int ml = lane & 15, q = lane >> 4;
  int row = mt * 16 + ml; if (row > N_ITEM - 1) row = N_ITEM - 1;
  size_t k0 = (size_t)kc * 256 + q * 8;
  const bh8* Ah = (const bh8*)(pool2h + (size_t)row * 8192 + k0);
  const bh8* Al = (const bh8*)(pool2l + (size_t)row * 8192 + k0);
  const bh8* Bh[4], * Bl[4];
#pragma unroll
  for (int nb = 0; nb < 4; ++nb) {
    Bh[nb] = (const bh8*)(whi + (size_t)(nb * 16 + ml) * 8192 + k0);
    Bl[nb] = (const bh8*)(wlo + (size_t)(nb * 16 + ml) * 8192 + k0);
  }
  f32x4 acc[4];
#pragma unroll
  for (int nb = 0; nb < 4; ++nb) acc[nb] = (f32x4){0.f, 0.f, 0.f, 0.f};
#pragma unroll
  for (int st = 0; st < 8; ++st) {
    bh8 ah = Ah[st * 4], al = Al[st * 4];
#pragma unroll
    for (int nb = 0; nb < 4; ++nb) {
      bh8 bhv = Bh[nb][st * 4], blv = Bl[nb][st * 4];
      acc[nb] = __builtin_amdgcn_mfma_f32_16x16x32_bf16(ah, bhv, acc[nb], 0, 0, 0);
      acc[nb] = __builtin_amdgcn_mfma_f32_16x16x32_bf16(ah, blv, acc[nb], 0, 0, 0);
      acc[nb] = __builtin_amdgcn_mfma_f32_16x16x32_bf16(al, bhv, acc[nb], 0, 0, 0);
    }
  }
#pragma unroll
  for (int r = 0; r < 4; ++r) {
    int mr = mt * 16 + q * 4 + r;
    if (mr < N_ITEM) {
      float* dst = xfc + (size_t)mr * 64 + ml;
#pragma unroll
      for (int nb = 0; nb < 4; ++nb) atomicAdd(dst + nb * 16, acc[nb][r]);
    }
  }
}

// ---------------- per-group, per-column batch norm (ddof=1) ----------------
__global__ __launch_bounds__(256) void k_norm(
    const float* __restrict__ xfc, float* __restrict__ item) {
  __shared__ float red[256];
  int grp = blockIdx.x >> 6;
  int o = blockIdx.x & 63;
  int base = grp ? N_CELL : 0;
  int N = grp ? N_DRUG : N_CELL;
  int tid = threadIdx.x;
  float s = 0.f;
  for (int i = tid; i < N; i += 256) s += xfc[(size_t)(base + i) * 64 + o];
  red[tid] = s; __syncthreads();
  for (int w = 128; w > 0; w >>= 1) { if (tid < w) red[tid] += red[tid + w]; __syncthreads(); }
  float mean = red[0] / (float)N;
  __syncthreads();
  float sq = 0.f;
  for (int i = tid; i < N; i += 256) {
    float d = xfc[(size_t)(base + i) * 64 + o] - mean;
    sq += d * d;
  }
  red[tid] = sq; __syncthreads();
  for (int w = 128; w > 0; w >>= 1) { if (tid < w) red[tid] += red[tid + w]; __syncthreads(); }
  float inv_std = 1.f / sqrtf(red[0] / (float)(N - 1));
  for (int i = tid; i < N; i += 256)
    item[(size_t)(base + i) * 64 + o] = (xfc[(size_t)(base + i) * 64 + o] - mean) * inv_std;
}

// ---------------- interact (2-hop attention) + agg GEMV ----------------
__global__ __launch_bounds__(256) void k_interact(
    const int* __restrict__ cell_nbr, const int* __restrict__ drug_nbr,
    const float* __restrict__ protein, const float* __restrict__ item,
    const float* __restrict__ agg_w, const float* __restrict__ agg_b,
    float* __restrict__ emb) {
  __shared__ float pb[128 * 65];
  __shared__ float item_s[64];
  __shared__ float sc[128];
  __shared__ float hop_out[128];
  __shared__ float red[256];
  int n = blockIdx.x;
  int tid = threadIdx.x;
  const int* nbr = (n < N_CELL) ? (cell_nbr + (size_t)n * 256)
                                : (drug_nbr + (size_t)(n - N_CELL) * 256);
  if (tid < 64) item_s[tid] = item[(size_t)n * 64 + tid];
  __syncthreads();
  for (int h = 0; h < 2; ++h) {
    for (int e = tid; e < 8192; e += 256) {
      int k = e >> 6, d = e & 63;
      int idx = nbr[h * 128 + k];
      pb[k * 65 + d] = protein[(size_t)idx * 64 + d];
    }
    __syncthreads();
    {
      int k = tid >> 1, halfd = tid & 1;
      int d0 = halfd * 32;
      float p = 0.f;
#pragma unroll
      for (int d = 0; d < 32; ++d) p += item_s[d0 + d] * pb[k * 65 + d0 + d];
      p += __shfl_xor(p, 1);
      if (halfd == 0) sc[k] = p;
    }
    __syncthreads();
    if (tid < 64) {
      float a = sc[tid], b = sc[tid + 64];
      float m = fmaxf(a, b);
#pragma unroll
      for (int off = 32; off > 0; off >>= 1) m = fmaxf(m, __shfl_xor(m, off));
      float e0 = __expf(a - m), e1 = __expf(b - m);
      float s = e0 + e1;
#pragma unroll
      for (int off = 32; off > 0; off >>= 1) s += __shfl_xor(s, off);
      float inv = 1.f / s;
      sc[tid] = e0 * inv; sc[tid + 64] = e1 * inv;
    }
    __syncthreads();
    {
      int d = tid & 63, kq = tid >> 6;
      float p = 0.f;
#pragma unroll
      for (int k = 0; k < 32; ++k) {
        int kk = kq * 32 + k;
        p += sc[kk] * pb[kk * 65 + d];
      }
      red[tid] = p;
    }
    __syncthreads();
    if (tid < 64)
      hop_out[h * 64 + tid] = red[tid] + red[tid + 64] + red[tid + 128] + red[tid + 192];
    __syncthreads();
  }
  {
    int o = tid & 63, jq = tid >> 6;
    float p = 0.f;
#pragma unroll
    for (int j = 0; j < 32; ++j) {
      int jj = jq * 32 + j;
      p += hop_out[jj] * agg_w[(size_t)o * 128 + jj];
    }
    red[tid] = p;
  }
  __syncthreads();
  if (tid < 64)
    emb[(size_t)n * 64 + tid] =
        red[tid] + red[tid + 64] + red[tid + 128] + red[tid + 192] + agg_b[tid];
}

// ---------------- precompute V[c] = comb_w^T @ cell_emb[c]  (76 x 128) ----------------
__global__ __launch_bounds__(128) void k_cellv(
    const float* __restrict__ emb, const float* __restrict__ comb_w,
    float* __restrict__ V) {
  __shared__ float ce[64];
  int c = blockIdx.x;
  int j = threadIdx.x;
  if (j < 64) ce[j] = emb[(size_t)c * 64 + j];
  __syncthreads();
  float s = 0.f;
#pragma unroll
  for (int o = 0; o < 64; ++o) s += comb_w[(size_t)o * 128 + j] * ce[o];
  V[(size_t)c * 128 + j] = s;
}

// ---------------- final scoring: therapy = cat(e1,e2) . V[c], toxic = e1.e2 ----------------
__global__ __launch_bounds__(256) void k_score(
    const int* __restrict__ data, const float* __restrict__ emb,
    const float* __restrict__ V, float* __restrict__ out,
    float* __restrict__ loss) {
  __shared__ float racc[4];
  int tid = threadIdx.x;
  int lane = tid & 63;
  int w = tid >> 6;
  int b = blockIdx.x * 4 + w;
  int c = data[b * 3 + 0], d1 = data[b * 3 + 1], d2 = data[b * 3 + 2];
  float ce = emb[(size_t)c * 64 + lane];
  float e1 = emb[(size_t)(N_CELL + d1) * 64 + lane];
  float e2 = emb[(size_t)(N_CELL + d2) * 64 + lane];
  float v1 = V[(size_t)c * 128 + lane];
  float v2 = V[(size_t)c * 128 + 64 + lane];
  float th = e1 * v1 + e2 * v2;
  float tx = e1 * e2;
  float rg = ce * ce + e1 * e1 + e2 * e2;
#pragma unroll
  for (int off = 32; off > 0; off >>= 1) {
    th += __shfl_xor(th, off);
    tx += __shfl_xor(tx, off);
    rg += __shfl_xor(rg, off);
  }
  if (lane == 0) { out[b] = th - tx; racc[w] = rg; }
  __syncthreads();
  if (tid == 0) atomicAdd(loss, 0.5f * (racc[0] + racc[1] + racc[2] + racc[3]));
}

// ---------------- node regularization (6 gathered rows) ----------------
__global__ __launch_bounds__(256) void k_nodereg(
    const int* __restrict__ data, const int* __restrict__ cell_nbr,
    const int* __restrict__ drug_nbr, const float* __restrict__ protein,
    float* __restrict__ loss) {
  __shared__ float red[256];
  int j = blockIdx.x;  // 0..5
  int hop = j / 3, which = j % 3;
  int row = data[hop * 3 + which];
  const int* nbr = (which == 0) ? (cell_nbr + (size_t)row * 256)
                                : (drug_nbr + (size_t)row * 256);
  int tid = threadIdx.x;
  float acc = 0.f;
  for (int e = tid; e < 16384; e += 256) {
    int k = e >> 6, d = e & 63;
    float v = protein[(size_t)nbr[k] * 64 + d];
    acc += v * v;
  }
  red[tid] = acc; __syncthreads();
  for (int w = 128; w > 0; w >>= 1) { if (tid < w) red[tid] += red[tid + w]; __syncthreads(); }
  if (tid == 0) atomicAdd(loss, 0.5f * red[0]);
}

__global__ void k_finalize(const float* __restrict__ loss, float* __restrict__ out) {
  if (threadIdx.x == 0) out[BATCH] = loss[0] * (1e-6f / 4096.f);
}

extern "C" void kernel_launch(void* const* d_in, const int* in_sizes, int n_in,
                              void* d_out, int out_size, void* d_ws, size_t ws_size,
                              hipStream_t stream) {
  const int*   data      = (const int*)d_in[0];
  const int*   cell_nbr  = (const int*)d_in[1];
  const int*   drug_nbr  = (const int*)d_in[2];
  const float* protein   = (const float*)d_in[3];
  const float* cell_pre  = (const float*)d_in[4];
  const float* drug_pre  = (const float*)d_in[5];
  const float* w1        = (const float*)d_in[6];
  const float* b1        = (const float*)d_in[7];
  const float* w2        = (const float*)d_in[8];
  const float* b2        = (const float*)d_in[9];
  const float* out_w     = (const float*)d_in[10];
  const float* agg_w     = (const float*)d_in[12];
  const float* agg_b     = (const float*)d_in[13];
  const float* comb_w    = (const float*)d_in[14];
  float* out = (float*)d_out;
  char* base = (char*)d_ws;
  float* pool1            = (float*)base;
  unsigned short* pool2h  = (unsigned short*)(base + POOL2H_B);
  unsigned short* pool2l  = (unsigned short*)(base + POOL2L_B);
  unsigned short* whi     = (unsigned short*)(base + WHI_B);
  unsigned short* wlo     = (unsigned short*)(base + WLO_B);
  float* xfc              = (float*)(base + XFC_B);
  float* item             = (float*)(base + ITEM_B);
  float* emb              = (float*)(base + EMB_B);
  float* V                = (float*)(base + V_B);
  float* loss             = (float*)(base + LOSS_B);

  k_conv1<<<dim3(4, 840), 256, 0, stream>>>(cell_pre, drug_pre, w1, b1, pool1);
  k_conv2<<<dim3(4, 840), 256, 0, stream>>>(pool1, w2, b2, pool2h, pool2l);
  k_cast<<<512, 256, 0, stream>>>(out_w, whi, wlo, xfc, loss);
  k_fc<<<dim3(53, 32), 64, 0, stream>>>(pool2h, pool2l, whi, wlo, xfc);
  k_norm<<<128, 256, 0, stream>>>(xfc, item);
  k_interact<<<840, 256, 0, stream>>>(cell_nbr, drug_nbr, protein, item, agg_w, agg_b, emb);
  k_cellv<<<N_CELL, 128, 0, stream>>>(emb, comb_w, V);
  k_score<<<1024, 256, 0, stream>>>(data, emb, V, out, loss);
  k_nodereg<<<6, 256, 0, stream>>>(data, cell_nbr, drug_nbr, protein, loss);
  k_finalize<<<1, 64, 0, stream>>>(loss, out);
}